// Round 2
// baseline (1241.859 us; speedup 1.0000x reference)
//
#include <hip/hip_runtime.h>

// 192^3 single-step fluid solver, fp32.
// Layout: [c, i, j, k], k fastest.
// R2: pressure solve restructured — k_p2 (iters 1-2, local stencil of div) +
//     9x k_jacobi2 (2 fused Jacobi iters via LDS plane-marching) = 20 iters.

constexpr int   N      = 192;
constexpr int   N2     = N * N;
constexpr int   N3     = N * N * N;
constexpr float GDT    = 9.81f * 0.01f;            // GRAV * DT
constexpr float SCL    = 0.01f / 0.1f;             // DT / H = 0.1
constexpr float ALPHA  = 0.01f * 0.01f / (0.1f * 0.1f);  // VISC*DT/H^2 = 0.01
constexpr float INVDIF = 1.0f / (1.0f + 6.0f * ALPHA);
constexpr float INV2H  = 1.0f / (2.0f * 0.1f);     // 5.0
constexpr float SIXTH  = 1.0f / 6.0f;

__device__ __forceinline__ bool is_bnd(int i, int j, int k) {
    return (i == 0) | (i == N - 1) | (j == 0) | (j == N - 1) | (k == 0) | (k == N - 1);
}

// ---------------- advect (+gravity) ----------------
__global__ __launch_bounds__(192) void k_advect(const float* __restrict__ vin,
                                                float* __restrict__ vout) {
    const int k  = threadIdx.x;
    const int j  = blockIdx.x;
    const int i  = blockIdx.y;
    const int id = (i * N + j) * N + k;

    const float vx = vin[id];
    const float vy = vin[id + N3];
    const float vz = vin[id + 2 * N3] - GDT;

    float px = (float)i - vx * SCL;
    float py = (float)j - vy * SCL;
    float pz = (float)k - vz * SCL;
    const float hi = (float)(N - 2);
    px = fminf(fmaxf(px, 0.0f), hi);
    py = fminf(fmaxf(py, 0.0f), hi);
    pz = fminf(fmaxf(pz, 0.0f), hi);

    const int ix = (int)px;
    const int iy = (int)py;
    const int iz = (int)pz;
    const float wx1 = px - (float)ix, wy1 = py - (float)iy, wz1 = pz - (float)iz;
    const float wx0 = 1.0f - wx1,     wy0 = 1.0f - wy1,     wz0 = 1.0f - wz1;

    const int base = (ix * N + iy) * N + iz;
    const float w000 = wx0 * wy0 * wz0;
    const float w001 = wx0 * wy0 * wz1;
    const float w010 = wx0 * wy1 * wz0;
    const float w011 = wx0 * wy1 * wz1;
    const float w100 = wx1 * wy0 * wz0;
    const float w101 = wx1 * wy0 * wz1;
    const float w110 = wx1 * wy1 * wz0;
    const float w111 = wx1 * wy1 * wz1;

#pragma unroll
    for (int c = 0; c < 3; ++c) {
        const float* f = vin + c * N3;
        float r = f[base]          * w000 + f[base + 1]          * w001
                + f[base + N]      * w010 + f[base + N + 1]      * w011
                + f[base + N2]     * w100 + f[base + N2 + 1]     * w101
                + f[base + N2 + N] * w110 + f[base + N2 + N + 1] * w111;
        if (c == 2) r -= GDT;
        vout[c * N3 + id] = r;
    }
}

// ---------------- diffuse (plain, per-component via blockIdx.z) ----------------
__global__ __launch_bounds__(192) void k_diffuse(const float* __restrict__ vin,
                                                 float* __restrict__ vout) {
    const int k  = threadIdx.x;
    const int j  = blockIdx.x;
    const int i  = blockIdx.y;
    const int id = blockIdx.z * N3 + (i * N + j) * N + k;
    const float v = vin[id];
    if (is_bnd(i, j, k)) { vout[id] = v; return; }
    const float nb = vin[id - N2] + vin[id + N2]
                   + vin[id - N]  + vin[id + N]
                   + vin[id - 1]  + vin[id + 1];
    vout[id] = (v + ALPHA * nb) * INVDIF;
}

// ---------------- divergence ----------------
__global__ __launch_bounds__(192) void k_div(const float* __restrict__ v,
                                             float* __restrict__ dv) {
    const int k  = threadIdx.x;
    const int j  = blockIdx.x;
    const int i  = blockIdx.y;
    const int id = (i * N + j) * N + k;
    if (is_bnd(i, j, k)) { dv[id] = 0.0f; return; }
    const float d = (v[id + N2]          - v[id - N2])
                  + (v[id + N3 + N]      - v[id + N3 - N])
                  + (v[id + 2 * N3 + 1]  - v[id + 2 * N3 - 1]);
    dv[id] = d * INV2H;
}

// ---------------- pressure iterations 1+2 fused (pure function of div) -------
// p1(y) = interior(y) ? dv(y)/6 : 0 ;  p2(x) = interior(x) ? (dv(x)+sum p1(nb))/6 : 0
__global__ __launch_bounds__(192) void k_p2(const float* __restrict__ dv,
                                            float* __restrict__ p) {
    const int k  = threadIdx.x;
    const int j  = blockIdx.x;
    const int i  = blockIdx.y;
    const int id = (i * N + j) * N + k;
    if (is_bnd(i, j, k)) { p[id] = 0.0f; return; }
    float nb = 0.0f;
    if (i > 1)     nb += dv[id - N2];
    if (i < N - 2) nb += dv[id + N2];
    if (j > 1)     nb += dv[id - N];
    if (j < N - 2) nb += dv[id + N];
    if (k > 1)     nb += dv[id - 1];
    if (k < N - 2) nb += dv[id + 1];
    p[id] = (dv[id] + nb * SIXTH) * SIXTH;
}

// ---------------- fused 2-iteration Jacobi (LDS plane-marching) ----------------
// pout = J(J(pin)). Tile (j,k)=32x32, i-chunk=12, rolling windows:
//   sp : pin, 5 planes, halo 2  (36x36)
//   sq : q=J(pin), 3 planes, halo 1 (34x34)
//   sdv: div, 2 planes, halo 1 (34x34)
constexpr int TJ = 32, TK = 32, CHUNK = 12;
constexpr int PJ = TJ + 4, PK = TK + 4;   // 36
constexpr int QJ = TJ + 2, QK = TK + 2;   // 34

__global__ __launch_bounds__(256) void k_jacobi2(const float* __restrict__ pin,
                                                 const float* __restrict__ dv,
                                                 float* __restrict__ pout) {
    __shared__ float sp[5 * PJ * PK];
    __shared__ float sq[3 * QJ * QK];
    __shared__ float sdv[2 * QJ * QK];

    const int tid = threadIdx.x;
    const int j0  = blockIdx.x * TJ;
    const int k0  = blockIdx.y * TK;
    const int i0  = blockIdx.z * CHUNK;

    auto loadP = [&](int ip) {
        const int ic = min(max(ip, 0), N - 1);
        const float* src = pin + ic * N2;
        float* dst = sp + ((ip + 5) % 5) * (PJ * PK);
        for (int idx = tid; idx < PJ * PK; idx += 256) {
            const int r = idx / PK, c = idx - r * PK;
            const int j = min(max(j0 - 2 + r, 0), N - 1);
            const int k = min(max(k0 - 2 + c, 0), N - 1);
            dst[idx] = src[j * N + k];
        }
    };

    auto loadDV = [&](int ip) {
        const int ic = min(max(ip, 0), N - 1);
        const float* src = dv + ic * N2;
        float* dst = sdv + ((ip + 2) % 2) * (QJ * QK);
        for (int idx = tid; idx < QJ * QK; idx += 256) {
            const int r = idx / QK, c = idx - r * QK;
            const int j = min(max(j0 - 1 + r, 0), N - 1);
            const int k = min(max(k0 - 1 + c, 0), N - 1);
            dst[idx] = src[j * N + k];
        }
    };

    auto computeQ = [&](int ip) {
        float* dst = sq + ((ip + 3) % 3) * (QJ * QK);
        const float* pm = sp + ((ip - 1 + 5) % 5) * (PJ * PK);
        const float* pc = sp + ((ip + 5) % 5) * (PJ * PK);
        const float* pp = sp + ((ip + 1 + 5) % 5) * (PJ * PK);
        const float* dd = sdv + ((ip + 2) % 2) * (QJ * QK);
        for (int idx = tid; idx < QJ * QK; idx += 256) {
            const int r = idx / QK, c = idx - r * QK;
            const int j = j0 - 1 + r, k = k0 - 1 + c;
            float val = 0.0f;
            if (ip > 0 && ip < N - 1 && j > 0 && j < N - 1 && k > 0 && k < N - 1) {
                const int b = (r + 1) * PK + (c + 1);
                const float nb = pm[b] + pp[b]
                               + pc[b - PK] + pc[b + PK]
                               + pc[b - 1]  + pc[b + 1];
                val = (dd[idx] + nb) * SIXTH;
            }
            dst[idx] = val;
        }
    };

    auto computeOut = [&](int ip) {
        const float* qm = sq + ((ip - 1 + 3) % 3) * (QJ * QK);
        const float* qc = sq + ((ip + 3) % 3) * (QJ * QK);
        const float* qp = sq + ((ip + 1 + 3) % 3) * (QJ * QK);
        const float* dd = sdv + ((ip + 2) % 2) * (QJ * QK);
        float* dst = pout + ip * N2;
        for (int idx = tid; idx < TJ * TK; idx += 256) {
            const int r = idx >> 5, c = idx & 31;
            const int j = j0 + r, k = k0 + c;
            float val = 0.0f;
            if (ip > 0 && ip < N - 1 && j > 0 && j < N - 1 && k > 0 && k < N - 1) {
                const int b = (r + 1) * QK + (c + 1);
                const float nb = qm[b] + qp[b]
                               + qc[b - QK] + qc[b + QK]
                               + qc[b - 1]  + qc[b + 1];
                val = (dd[b] + nb) * SIXTH;
            }
            dst[j * N + k] = val;
        }
    };

    // prologue: pin planes i0-2..i0+1, dv planes i0-1..i0, q planes i0-1..i0
    loadP(i0 - 2); loadP(i0 - 1); loadP(i0); loadP(i0 + 1);
    loadDV(i0 - 1); loadDV(i0);
    __syncthreads();
    computeQ(i0 - 1);
    computeQ(i0);
    __syncthreads();

    for (int io = i0; io < i0 + CHUNK; ++io) {
        loadP(io + 2);
        loadDV(io + 1);
        __syncthreads();
        computeQ(io + 1);
        __syncthreads();
        computeOut(io);
        __syncthreads();   // WAR: next iter's loads overwrite slots just read
    }
}

// ---------------- gradient subtract (in-place on vel interior) ----------------
__global__ __launch_bounds__(192) void k_grad(float* __restrict__ vel,
                                              const float* __restrict__ p) {
    const int k  = threadIdx.x;
    const int j  = blockIdx.x;
    const int i  = blockIdx.y;
    const int id = (i * N + j) * N + k;
    if (is_bnd(i, j, k)) return;
    vel[id]          -= (p[id + N2] - p[id - N2]) * INV2H;
    vel[id + N3]     -= (p[id + N]  - p[id - N])  * INV2H;
    vel[id + 2 * N3] -= (p[id + 1]  - p[id - 1])  * INV2H;
}

extern "C" void kernel_launch(void* const* d_in, const int* in_sizes, int n_in,
                              void* d_out, int out_size, void* d_ws, size_t ws_size,
                              hipStream_t stream) {
    const float* vin  = (const float*)d_in[0];
    float*       vout = (float*)d_out;
    float*       ws   = (float*)d_ws;

    // ws layout: phase 1 velB = ws[0..3N3); phase 2 (velB dead):
    //   dv = ws[0..N3), pA = ws[N3..2N3), pB = ws[2N3..3N3)
    float* velB = ws;
    float* dv   = ws;
    float* pA   = ws + N3;
    float* pB   = ws + 2 * N3;

    const dim3 blk(N, 1, 1);
    const dim3 grid1(N, N, 1);
    const dim3 grid3(N, N, 3);
    const dim3 blkJ(256, 1, 1);
    const dim3 gridJ(N / TJ, N / TK, N / CHUNK);   // 6 x 6 x 16

    // gravity + advect: vin -> velB
    k_advect<<<grid1, blk, 0, stream>>>(vin, velB);

    // 5 diffusion sweeps, ping-pong; ends in vout
    k_diffuse<<<grid3, blk, 0, stream>>>(velB, vout);
    k_diffuse<<<grid3, blk, 0, stream>>>(vout, velB);
    k_diffuse<<<grid3, blk, 0, stream>>>(velB, vout);
    k_diffuse<<<grid3, blk, 0, stream>>>(vout, velB);
    k_diffuse<<<grid3, blk, 0, stream>>>(velB, vout);

    // projection
    k_div<<<grid1, blk, 0, stream>>>(vout, dv);
    k_p2<<<grid1, blk, 0, stream>>>(dv, pA);           // iterations 1-2
    float* pin  = pA;
    float* pout = pB;
    for (int s = 0; s < 9; ++s) {                      // iterations 3..20
        k_jacobi2<<<gridJ, blkJ, 0, stream>>>(pin, dv, pout);
        float* t = pin; pin = pout; pout = t;
    }
    k_grad<<<grid1, blk, 0, stream>>>(vout, pin);      // in-place on d_out
}

// Round 3
// 801.392 us; speedup vs baseline: 1.5496x; 1.5496x over previous
//
#include <hip/hip_runtime.h>

// 192^3 single-step fluid solver, fp32.
// Layout: [c, i, j, k], k fastest.
// R3: all stencil sweeps vectorized float4 (4 k-cells per thread) — cuts vmem
//     instruction count 4x vs scalar (sweeps were issue/latency bound, not BW
//     bound: ~30us measured vs ~6us traffic floor). Fusion (R2) reverted.

constexpr int   N      = 192;
constexpr int   N2     = N * N;
constexpr int   N3     = N * N * N;
constexpr float GDT    = 9.81f * 0.01f;            // GRAV * DT
constexpr float SCL    = 0.01f / 0.1f;             // DT / H = 0.1
constexpr float ALPHA  = 0.01f * 0.01f / (0.1f * 0.1f);  // VISC*DT/H^2 = 0.01
constexpr float INVDIF = 1.0f / (1.0f + 6.0f * ALPHA);
constexpr float INV2H  = 1.0f / (2.0f * 0.1f);     // 5.0
constexpr float SIXTH  = 1.0f / 6.0f;

constexpr int NT4 = (N3 / 4) / 256;   // 6912 blocks of 256 threads, 4 cells/thread

// decompose id (multiple of 4) -> i, j, k0
__device__ __forceinline__ void decomp(int id, int& i, int& j, int& k0) {
    i = id / N2;                 // magic-mul, constant divisor
    const int r = id - i * N2;
    j = r / N;
    k0 = r - j * N;
}

// ---------------- advect (+gravity), unchanged from R1 ----------------
__global__ __launch_bounds__(192) void k_advect(const float* __restrict__ vin,
                                                float* __restrict__ vout) {
    const int k  = threadIdx.x;
    const int j  = blockIdx.x;
    const int i  = blockIdx.y;
    const int id = (i * N + j) * N + k;

    const float vx = vin[id];
    const float vy = vin[id + N3];
    const float vz = vin[id + 2 * N3] - GDT;

    float px = (float)i - vx * SCL;
    float py = (float)j - vy * SCL;
    float pz = (float)k - vz * SCL;
    const float hi = (float)(N - 2);
    px = fminf(fmaxf(px, 0.0f), hi);
    py = fminf(fmaxf(py, 0.0f), hi);
    pz = fminf(fmaxf(pz, 0.0f), hi);

    const int ix = (int)px;
    const int iy = (int)py;
    const int iz = (int)pz;
    const float wx1 = px - (float)ix, wy1 = py - (float)iy, wz1 = pz - (float)iz;
    const float wx0 = 1.0f - wx1,     wy0 = 1.0f - wy1,     wz0 = 1.0f - wz1;

    const int base = (ix * N + iy) * N + iz;
    const float w000 = wx0 * wy0 * wz0;
    const float w001 = wx0 * wy0 * wz1;
    const float w010 = wx0 * wy1 * wz0;
    const float w011 = wx0 * wy1 * wz1;
    const float w100 = wx1 * wy0 * wz0;
    const float w101 = wx1 * wy0 * wz1;
    const float w110 = wx1 * wy1 * wz0;
    const float w111 = wx1 * wy1 * wz1;

#pragma unroll
    for (int c = 0; c < 3; ++c) {
        const float* f = vin + c * N3;
        float r = f[base]          * w000 + f[base + 1]          * w001
                + f[base + N]      * w010 + f[base + N + 1]      * w011
                + f[base + N2]     * w100 + f[base + N2 + 1]     * w101
                + f[base + N2 + N] * w110 + f[base + N2 + N + 1] * w111;
        if (c == 2) r -= GDT;
        vout[c * N3 + id] = r;
    }
}

// ---------------- diffuse, float4, component = blockIdx.y ----------------
__global__ __launch_bounds__(256) void k_diffuse4(const float* __restrict__ vin,
                                                  float* __restrict__ vout) {
    const int gtid = blockIdx.x * 256 + threadIdx.x;
    const int id   = gtid << 2;
    int i, j, k0; decomp(id, i, j, k0);
    const int b = blockIdx.y * N3 + id;

    const float4 c = *(const float4*)(vin + b);
    float4 out = c;
    if (i != 0 && i != N - 1 && j != 0 && j != N - 1) {
        const float4 ip = *(const float4*)(vin + b + N2);
        const float4 im = *(const float4*)(vin + b - N2);
        const float4 jp = *(const float4*)(vin + b + N);
        const float4 jm = *(const float4*)(vin + b - N);
        const float  km = (k0 > 0)     ? vin[b - 1] : 0.0f;
        const float  kp = (k0 < N - 4) ? vin[b + 4] : 0.0f;
        out.x = (c.x + ALPHA * (im.x + ip.x + jm.x + jp.x + km  + c.y)) * INVDIF;
        out.y = (c.y + ALPHA * (im.y + ip.y + jm.y + jp.y + c.x + c.z)) * INVDIF;
        out.z = (c.z + ALPHA * (im.z + ip.z + jm.z + jp.z + c.y + c.w)) * INVDIF;
        out.w = (c.w + ALPHA * (im.w + ip.w + jm.w + jp.w + c.z + kp )) * INVDIF;
        if (k0 == 0)     out.x = c.x;   // k boundary: copy
        if (k0 == N - 4) out.w = c.w;
    }
    *(float4*)(vout + b) = out;
}

// ---------------- divergence, float4 ----------------
__global__ __launch_bounds__(256) void k_div4(const float* __restrict__ v,
                                              float* __restrict__ dv) {
    const int gtid = blockIdx.x * 256 + threadIdx.x;
    const int id   = gtid << 2;
    int i, j, k0; decomp(id, i, j, k0);

    float4 out = make_float4(0.f, 0.f, 0.f, 0.f);
    if (i != 0 && i != N - 1 && j != 0 && j != N - 1) {
        const float4 xp = *(const float4*)(v + id + N2);
        const float4 xm = *(const float4*)(v + id - N2);
        const float4 yp = *(const float4*)(v + N3 + id + N);
        const float4 ym = *(const float4*)(v + N3 + id - N);
        const float4 z  = *(const float4*)(v + 2 * N3 + id);
        const float  zm = (k0 > 0)     ? v[2 * N3 + id - 1] : 0.0f;
        const float  zp = (k0 < N - 4) ? v[2 * N3 + id + 4] : 0.0f;
        out.x = ((xp.x - xm.x) + (yp.x - ym.x) + (z.y - zm )) * INV2H;
        out.y = ((xp.y - xm.y) + (yp.y - ym.y) + (z.z - z.x)) * INV2H;
        out.z = ((xp.z - xm.z) + (yp.z - ym.z) + (z.w - z.y)) * INV2H;
        out.w = ((xp.w - xm.w) + (yp.w - ym.w) + (zp  - z.z)) * INV2H;
        if (k0 == 0)     out.x = 0.f;
        if (k0 == N - 4) out.w = 0.f;
    }
    *(float4*)(dv + id) = out;
}

// ---------------- pressure iterations 1+2 fused, float4 ----------------
// dv == 0 on all boundaries, so neighbor guards are free: p1 = dv/6 everywhere,
// p2 = (dv + sum(p1 nb))/6 on interior, 0 on boundary.
__global__ __launch_bounds__(256) void k_p2_4(const float* __restrict__ dv,
                                              float* __restrict__ p) {
    const int gtid = blockIdx.x * 256 + threadIdx.x;
    const int id   = gtid << 2;
    int i, j, k0; decomp(id, i, j, k0);

    float4 out = make_float4(0.f, 0.f, 0.f, 0.f);
    if (i != 0 && i != N - 1 && j != 0 && j != N - 1) {
        const float4 c  = *(const float4*)(dv + id);
        const float4 ip = *(const float4*)(dv + id + N2);
        const float4 im = *(const float4*)(dv + id - N2);
        const float4 jp = *(const float4*)(dv + id + N);
        const float4 jm = *(const float4*)(dv + id - N);
        const float  km = (k0 > 0)     ? dv[id - 1] : 0.0f;
        const float  kp = (k0 < N - 4) ? dv[id + 4] : 0.0f;
        out.x = (c.x + (im.x + ip.x + jm.x + jp.x + km  + c.y) * SIXTH) * SIXTH;
        out.y = (c.y + (im.y + ip.y + jm.y + jp.y + c.x + c.z) * SIXTH) * SIXTH;
        out.z = (c.z + (im.z + ip.z + jm.z + jp.z + c.y + c.w) * SIXTH) * SIXTH;
        out.w = (c.w + (im.w + ip.w + jm.w + jp.w + c.z + kp ) * SIXTH) * SIXTH;
        if (k0 == 0)     out.x = 0.f;
        if (k0 == N - 4) out.w = 0.f;
    }
    *(float4*)(p + id) = out;
}

// ---------------- pressure Jacobi sweep, float4 ----------------
// pin == 0 on all boundaries (invariant), so neighbor loads need no guards.
__global__ __launch_bounds__(256) void k_jacobi4(const float* __restrict__ pin,
                                                 const float* __restrict__ dv,
                                                 float* __restrict__ pout) {
    const int gtid = blockIdx.x * 256 + threadIdx.x;
    const int id   = gtid << 2;
    int i, j, k0; decomp(id, i, j, k0);

    float4 out = make_float4(0.f, 0.f, 0.f, 0.f);
    if (i != 0 && i != N - 1 && j != 0 && j != N - 1) {
        const float4 c  = *(const float4*)(pin + id);
        const float4 ip = *(const float4*)(pin + id + N2);
        const float4 im = *(const float4*)(pin + id - N2);
        const float4 jp = *(const float4*)(pin + id + N);
        const float4 jm = *(const float4*)(pin + id - N);
        const float4 d  = *(const float4*)(dv + id);
        const float  km = (k0 > 0)     ? pin[id - 1] : 0.0f;
        const float  kp = (k0 < N - 4) ? pin[id + 4] : 0.0f;
        out.x = (d.x + im.x + ip.x + jm.x + jp.x + km  + c.y) * SIXTH;
        out.y = (d.y + im.y + ip.y + jm.y + jp.y + c.x + c.z) * SIXTH;
        out.z = (d.z + im.z + ip.z + jm.z + jp.z + c.y + c.w) * SIXTH;
        out.w = (d.w + im.w + ip.w + jm.w + jp.w + c.z + kp ) * SIXTH;
        if (k0 == 0)     out.x = 0.f;
        if (k0 == N - 4) out.w = 0.f;
    }
    *(float4*)(pout + id) = out;
}

// ---------------- gradient subtract, float4, in-place on vel ----------------
__global__ __launch_bounds__(256) void k_grad4(float* __restrict__ vel,
                                               const float* __restrict__ p) {
    const int gtid = blockIdx.x * 256 + threadIdx.x;
    const int id   = gtid << 2;
    int i, j, k0; decomp(id, i, j, k0);
    if (i == 0 || i == N - 1 || j == 0 || j == N - 1) return;

    const float4 xp = *(const float4*)(p + id + N2);
    const float4 xm = *(const float4*)(p + id - N2);
    const float4 yp = *(const float4*)(p + id + N);
    const float4 ym = *(const float4*)(p + id - N);
    const float4 c  = *(const float4*)(p + id);
    const float  pm = (k0 > 0)     ? p[id - 1] : 0.0f;
    const float  pp = (k0 < N - 4) ? p[id + 4] : 0.0f;

    const bool bx = (k0 == 0);        // lane x is k-boundary
    const bool bw = (k0 == N - 4);    // lane w is k-boundary

    float4 v0 = *(float4*)(vel + id);
    if (!bx) v0.x -= (xp.x - xm.x) * INV2H;
             v0.y -= (xp.y - xm.y) * INV2H;
             v0.z -= (xp.z - xm.z) * INV2H;
    if (!bw) v0.w -= (xp.w - xm.w) * INV2H;
    *(float4*)(vel + id) = v0;

    float4 v1 = *(float4*)(vel + N3 + id);
    if (!bx) v1.x -= (yp.x - ym.x) * INV2H;
             v1.y -= (yp.y - ym.y) * INV2H;
             v1.z -= (yp.z - ym.z) * INV2H;
    if (!bw) v1.w -= (yp.w - ym.w) * INV2H;
    *(float4*)(vel + N3 + id) = v1;

    float4 v2 = *(float4*)(vel + 2 * N3 + id);
    if (!bx) v2.x -= (c.y - pm ) * INV2H;
             v2.y -= (c.z - c.x) * INV2H;
             v2.z -= (c.w - c.y) * INV2H;
    if (!bw) v2.w -= (pp  - c.z) * INV2H;
    *(float4*)(vel + 2 * N3 + id) = v2;
}

extern "C" void kernel_launch(void* const* d_in, const int* in_sizes, int n_in,
                              void* d_out, int out_size, void* d_ws, size_t ws_size,
                              hipStream_t stream) {
    const float* vin  = (const float*)d_in[0];
    float*       vout = (float*)d_out;
    float*       ws   = (float*)d_ws;

    // ws layout: phase 1 velB = ws[0..3N3); phase 2 (velB dead):
    //   dv = ws[0..N3), pA = ws[N3..2N3), pB = ws[2N3..3N3)
    float* velB = ws;
    float* dv   = ws;
    float* pA   = ws + N3;
    float* pB   = ws + 2 * N3;

    const dim3 blk(N, 1, 1);
    const dim3 grid1(N, N, 1);
    const dim3 blk4(256, 1, 1);
    const dim3 grid4_1(NT4, 1, 1);
    const dim3 grid4_3(NT4, 3, 1);

    // gravity + advect: vin -> velB
    k_advect<<<grid1, blk, 0, stream>>>(vin, velB);

    // 5 diffusion sweeps, ping-pong; ends in vout
    k_diffuse4<<<grid4_3, blk4, 0, stream>>>(velB, vout);
    k_diffuse4<<<grid4_3, blk4, 0, stream>>>(vout, velB);
    k_diffuse4<<<grid4_3, blk4, 0, stream>>>(velB, vout);
    k_diffuse4<<<grid4_3, blk4, 0, stream>>>(vout, velB);
    k_diffuse4<<<grid4_3, blk4, 0, stream>>>(velB, vout);

    // projection
    k_div4<<<grid4_1, blk4, 0, stream>>>(vout, dv);
    k_p2_4<<<grid4_1, blk4, 0, stream>>>(dv, pA);        // iterations 1-2
    float* pin  = pA;
    float* pout = pB;
    for (int s = 0; s < 9; ++s) {                        // iterations 3..20
        k_jacobi4<<<grid4_1, blk4, 0, stream>>>(pin, dv, pout);
        float* t = pin; pin = pout; pout = t;
        k_jacobi4<<<grid4_1, blk4, 0, stream>>>(pin, dv, pout);
        float* t2 = pin; pin = pout; pout = t2;
    }
    // 9*2 = 18 sweeps after p2's 2 => 20 total
    k_grad4<<<grid4_1, blk4, 0, stream>>>(vout, pin);    // in-place on d_out
}

// Round 4
// 644.640 us; speedup vs baseline: 1.9264x; 1.2432x over previous
//
#include <hip/hip_runtime.h>

// 192^3 single-step fluid solver, fp32.
// Layout: [c, i, j, k], k fastest.
// R4: (a) advect gather loads batched into independent g[3][8] for MLP;
//     (b) XCD-slab swizzle on ALL kernels: blockid%8 = XCD owns a contiguous
//         24-plane i-slab -> halo reuse stays in per-XCD L2 (was cross-XCD).
//     Sweep kernels otherwise unchanged from R3 (float4, 4 cells/thread).

constexpr int   N      = 192;
constexpr int   N2     = N * N;
constexpr int   N3     = N * N * N;
constexpr float GDT    = 9.81f * 0.01f;            // GRAV * DT
constexpr float SCL    = 0.01f / 0.1f;             // DT / H = 0.1
constexpr float ALPHA  = 0.01f * 0.01f / (0.1f * 0.1f);  // VISC*DT/H^2 = 0.01
constexpr float INVDIF = 1.0f / (1.0f + 6.0f * ALPHA);
constexpr float INV2H  = 1.0f / (2.0f * 0.1f);     // 5.0
constexpr float SIXTH  = 1.0f / 6.0f;

constexpr int NT4 = (N3 / 4) / 256;   // 6912 blocks of 256 threads, 4 cells/thread
constexpr int SLAB = NT4 / 8;         // 864 blocks per XCD slab (= 24 i-planes)

// XCD-slab swizzle for the 1-D float4 kernels: blocks b%8==x form slab x,
// processed in address order -> contiguous 24-plane region per XCD.
__device__ __forceinline__ int swz(int b) {
    return (b & 7) * SLAB + (b >> 3);
}

// decompose id (multiple of 4) -> i, j, k0
__device__ __forceinline__ void decomp(int id, int& i, int& j, int& k0) {
    i = id / N2;
    const int r = id - i * N2;
    j = r / N;
    k0 = r - j * N;
}

// ---------------- advect (+gravity) ----------------
// block = 192 threads (one k-row). Swizzle: XCD x owns i-slab [24x,24x+24),
// i fastest within slab, then j -> gather window per XCD ~3 j-rows x 26 i-rows
// x 3 comps ~ 180 KB, fits 4 MiB L2.
__global__ __launch_bounds__(192) void k_advect(const float* __restrict__ vin,
                                                float* __restrict__ vout) {
    const int k   = threadIdx.x;
    const int lin = blockIdx.y * 192 + blockIdx.x;   // hw dispatch order, x fastest
    const int x   = lin & 7;                         // XCD
    const int q   = lin >> 3;                        // 0..4607
    const int il  = q % 24;
    const int j   = q / 24;                          // 0..191
    const int i   = x * 24 + il;
    const int id  = (i * N + j) * N + k;

    const float vx = vin[id];
    const float vy = vin[id + N3];
    const float vz = vin[id + 2 * N3] - GDT;

    float px = (float)i - vx * SCL;
    float py = (float)j - vy * SCL;
    float pz = (float)k - vz * SCL;
    const float hi = (float)(N - 2);
    px = fminf(fmaxf(px, 0.0f), hi);
    py = fminf(fmaxf(py, 0.0f), hi);
    pz = fminf(fmaxf(pz, 0.0f), hi);

    const int ix = (int)px;
    const int iy = (int)py;
    const int iz = (int)pz;
    const int base = (ix * N + iy) * N + iz;

    // ---- all 24 gather loads issued as one independent batch (MLP) ----
    float g[3][8];
#pragma unroll
    for (int c = 0; c < 3; ++c) {
        const float* f = vin + c * N3 + base;
        g[c][0] = f[0];      g[c][1] = f[1];
        g[c][2] = f[N];      g[c][3] = f[N + 1];
        g[c][4] = f[N2];     g[c][5] = f[N2 + 1];
        g[c][6] = f[N2 + N]; g[c][7] = f[N2 + N + 1];
    }

    const float wx1 = px - (float)ix, wy1 = py - (float)iy, wz1 = pz - (float)iz;
    const float wx0 = 1.0f - wx1,     wy0 = 1.0f - wy1,     wz0 = 1.0f - wz1;
    const float w000 = wx0 * wy0 * wz0;
    const float w001 = wx0 * wy0 * wz1;
    const float w010 = wx0 * wy1 * wz0;
    const float w011 = wx0 * wy1 * wz1;
    const float w100 = wx1 * wy0 * wz0;
    const float w101 = wx1 * wy0 * wz1;
    const float w110 = wx1 * wy1 * wz0;
    const float w111 = wx1 * wy1 * wz1;

#pragma unroll
    for (int c = 0; c < 3; ++c) {
        float r = g[c][0] * w000 + g[c][1] * w001
                + g[c][2] * w010 + g[c][3] * w011
                + g[c][4] * w100 + g[c][5] * w101
                + g[c][6] * w110 + g[c][7] * w111;
        if (c == 2) r -= GDT;
        vout[c * N3 + id] = r;
    }
}

// ---------------- diffuse, float4, component = blockIdx.y ----------------
__global__ __launch_bounds__(256) void k_diffuse4(const float* __restrict__ vin,
                                                  float* __restrict__ vout) {
    const int gtid = swz(blockIdx.x) * 256 + threadIdx.x;
    const int id   = gtid << 2;
    int i, j, k0; decomp(id, i, j, k0);
    const int b = blockIdx.y * N3 + id;

    const float4 c = *(const float4*)(vin + b);
    float4 out = c;
    if (i != 0 && i != N - 1 && j != 0 && j != N - 1) {
        const float4 ip = *(const float4*)(vin + b + N2);
        const float4 im = *(const float4*)(vin + b - N2);
        const float4 jp = *(const float4*)(vin + b + N);
        const float4 jm = *(const float4*)(vin + b - N);
        const float  km = (k0 > 0)     ? vin[b - 1] : 0.0f;
        const float  kp = (k0 < N - 4) ? vin[b + 4] : 0.0f;
        out.x = (c.x + ALPHA * (im.x + ip.x + jm.x + jp.x + km  + c.y)) * INVDIF;
        out.y = (c.y + ALPHA * (im.y + ip.y + jm.y + jp.y + c.x + c.z)) * INVDIF;
        out.z = (c.z + ALPHA * (im.z + ip.z + jm.z + jp.z + c.y + c.w)) * INVDIF;
        out.w = (c.w + ALPHA * (im.w + ip.w + jm.w + jp.w + c.z + kp )) * INVDIF;
        if (k0 == 0)     out.x = c.x;
        if (k0 == N - 4) out.w = c.w;
    }
    *(float4*)(vout + b) = out;
}

// ---------------- divergence, float4 ----------------
__global__ __launch_bounds__(256) void k_div4(const float* __restrict__ v,
                                              float* __restrict__ dv) {
    const int gtid = swz(blockIdx.x) * 256 + threadIdx.x;
    const int id   = gtid << 2;
    int i, j, k0; decomp(id, i, j, k0);

    float4 out = make_float4(0.f, 0.f, 0.f, 0.f);
    if (i != 0 && i != N - 1 && j != 0 && j != N - 1) {
        const float4 xp = *(const float4*)(v + id + N2);
        const float4 xm = *(const float4*)(v + id - N2);
        const float4 yp = *(const float4*)(v + N3 + id + N);
        const float4 ym = *(const float4*)(v + N3 + id - N);
        const float4 z  = *(const float4*)(v + 2 * N3 + id);
        const float  zm = (k0 > 0)     ? v[2 * N3 + id - 1] : 0.0f;
        const float  zp = (k0 < N - 4) ? v[2 * N3 + id + 4] : 0.0f;
        out.x = ((xp.x - xm.x) + (yp.x - ym.x) + (z.y - zm )) * INV2H;
        out.y = ((xp.y - xm.y) + (yp.y - ym.y) + (z.z - z.x)) * INV2H;
        out.z = ((xp.z - xm.z) + (yp.z - ym.z) + (z.w - z.y)) * INV2H;
        out.w = ((xp.w - xm.w) + (yp.w - ym.w) + (zp  - z.z)) * INV2H;
        if (k0 == 0)     out.x = 0.f;
        if (k0 == N - 4) out.w = 0.f;
    }
    *(float4*)(dv + id) = out;
}

// ---------------- pressure iterations 1+2 fused, float4 ----------------
__global__ __launch_bounds__(256) void k_p2_4(const float* __restrict__ dv,
                                              float* __restrict__ p) {
    const int gtid = swz(blockIdx.x) * 256 + threadIdx.x;
    const int id   = gtid << 2;
    int i, j, k0; decomp(id, i, j, k0);

    float4 out = make_float4(0.f, 0.f, 0.f, 0.f);
    if (i != 0 && i != N - 1 && j != 0 && j != N - 1) {
        const float4 c  = *(const float4*)(dv + id);
        const float4 ip = *(const float4*)(dv + id + N2);
        const float4 im = *(const float4*)(dv + id - N2);
        const float4 jp = *(const float4*)(dv + id + N);
        const float4 jm = *(const float4*)(dv + id - N);
        const float  km = (k0 > 0)     ? dv[id - 1] : 0.0f;
        const float  kp = (k0 < N - 4) ? dv[id + 4] : 0.0f;
        out.x = (c.x + (im.x + ip.x + jm.x + jp.x + km  + c.y) * SIXTH) * SIXTH;
        out.y = (c.y + (im.y + ip.y + jm.y + jp.y + c.x + c.z) * SIXTH) * SIXTH;
        out.z = (c.z + (im.z + ip.z + jm.z + jp.z + c.y + c.w) * SIXTH) * SIXTH;
        out.w = (c.w + (im.w + ip.w + jm.w + jp.w + c.z + kp ) * SIXTH) * SIXTH;
        if (k0 == 0)     out.x = 0.f;
        if (k0 == N - 4) out.w = 0.f;
    }
    *(float4*)(p + id) = out;
}

// ---------------- pressure Jacobi sweep, float4 ----------------
__global__ __launch_bounds__(256) void k_jacobi4(const float* __restrict__ pin,
                                                 const float* __restrict__ dv,
                                                 float* __restrict__ pout) {
    const int gtid = swz(blockIdx.x) * 256 + threadIdx.x;
    const int id   = gtid << 2;
    int i, j, k0; decomp(id, i, j, k0);

    float4 out = make_float4(0.f, 0.f, 0.f, 0.f);
    if (i != 0 && i != N - 1 && j != 0 && j != N - 1) {
        const float4 c  = *(const float4*)(pin + id);
        const float4 ip = *(const float4*)(pin + id + N2);
        const float4 im = *(const float4*)(pin + id - N2);
        const float4 jp = *(const float4*)(pin + id + N);
        const float4 jm = *(const float4*)(pin + id - N);
        const float4 d  = *(const float4*)(dv + id);
        const float  km = (k0 > 0)     ? pin[id - 1] : 0.0f;
        const float  kp = (k0 < N - 4) ? pin[id + 4] : 0.0f;
        out.x = (d.x + im.x + ip.x + jm.x + jp.x + km  + c.y) * SIXTH;
        out.y = (d.y + im.y + ip.y + jm.y + jp.y + c.x + c.z) * SIXTH;
        out.z = (d.z + im.z + ip.z + jm.z + jp.z + c.y + c.w) * SIXTH;
        out.w = (d.w + im.w + ip.w + jm.w + jp.w + c.z + kp ) * SIXTH;
        if (k0 == 0)     out.x = 0.f;
        if (k0 == N - 4) out.w = 0.f;
    }
    *(float4*)(pout + id) = out;
}

// ---------------- gradient subtract, float4, in-place on vel ----------------
__global__ __launch_bounds__(256) void k_grad4(float* __restrict__ vel,
                                               const float* __restrict__ p) {
    const int gtid = swz(blockIdx.x) * 256 + threadIdx.x;
    const int id   = gtid << 2;
    int i, j, k0; decomp(id, i, j, k0);
    if (i == 0 || i == N - 1 || j == 0 || j == N - 1) return;

    const float4 xp = *(const float4*)(p + id + N2);
    const float4 xm = *(const float4*)(p + id - N2);
    const float4 yp = *(const float4*)(p + id + N);
    const float4 ym = *(const float4*)(p + id - N);
    const float4 c  = *(const float4*)(p + id);
    const float  pm = (k0 > 0)     ? p[id - 1] : 0.0f;
    const float  pp = (k0 < N - 4) ? p[id + 4] : 0.0f;

    const bool bx = (k0 == 0);
    const bool bw = (k0 == N - 4);

    float4 v0 = *(float4*)(vel + id);
    if (!bx) v0.x -= (xp.x - xm.x) * INV2H;
             v0.y -= (xp.y - xm.y) * INV2H;
             v0.z -= (xp.z - xm.z) * INV2H;
    if (!bw) v0.w -= (xp.w - xm.w) * INV2H;
    *(float4*)(vel + id) = v0;

    float4 v1 = *(float4*)(vel + N3 + id);
    if (!bx) v1.x -= (yp.x - ym.x) * INV2H;
             v1.y -= (yp.y - ym.y) * INV2H;
             v1.z -= (yp.z - ym.z) * INV2H;
    if (!bw) v1.w -= (yp.w - ym.w) * INV2H;
    *(float4*)(vel + N3 + id) = v1;

    float4 v2 = *(float4*)(vel + 2 * N3 + id);
    if (!bx) v2.x -= (c.y - pm ) * INV2H;
             v2.y -= (c.z - c.x) * INV2H;
             v2.z -= (c.w - c.y) * INV2H;
    if (!bw) v2.w -= (pp  - c.z) * INV2H;
    *(float4*)(vel + 2 * N3 + id) = v2;
}

extern "C" void kernel_launch(void* const* d_in, const int* in_sizes, int n_in,
                              void* d_out, int out_size, void* d_ws, size_t ws_size,
                              hipStream_t stream) {
    const float* vin  = (const float*)d_in[0];
    float*       vout = (float*)d_out;
    float*       ws   = (float*)d_ws;

    // ws layout: phase 1 velB = ws[0..3N3); phase 2 (velB dead):
    //   dv = ws[0..N3), pA = ws[N3..2N3), pB = ws[2N3..3N3)
    float* velB = ws;
    float* dv   = ws;
    float* pA   = ws + N3;
    float* pB   = ws + 2 * N3;

    const dim3 blk(N, 1, 1);
    const dim3 grid1(N, N, 1);
    const dim3 blk4(256, 1, 1);
    const dim3 grid4_1(NT4, 1, 1);
    const dim3 grid4_3(NT4, 3, 1);

    // gravity + advect: vin -> velB
    k_advect<<<grid1, blk, 0, stream>>>(vin, velB);

    // 5 diffusion sweeps, ping-pong; ends in vout
    k_diffuse4<<<grid4_3, blk4, 0, stream>>>(velB, vout);
    k_diffuse4<<<grid4_3, blk4, 0, stream>>>(vout, velB);
    k_diffuse4<<<grid4_3, blk4, 0, stream>>>(velB, vout);
    k_diffuse4<<<grid4_3, blk4, 0, stream>>>(vout, velB);
    k_diffuse4<<<grid4_3, blk4, 0, stream>>>(velB, vout);

    // projection
    k_div4<<<grid4_1, blk4, 0, stream>>>(vout, dv);
    k_p2_4<<<grid4_1, blk4, 0, stream>>>(dv, pA);        // iterations 1-2
    float* pin  = pA;
    float* pout = pB;
    for (int s = 0; s < 18; ++s) {                       // iterations 3..20
        k_jacobi4<<<grid4_1, blk4, 0, stream>>>(pin, dv, pout);
        float* t = pin; pin = pout; pout = t;
    }
    k_grad4<<<grid4_1, blk4, 0, stream>>>(vout, pin);    // in-place on d_out
}

// Round 5
// 573.595 us; speedup vs baseline: 2.1650x; 1.1239x over previous
//
#include <hip/hip_runtime.h>
#include <hip/hip_fp16.h>

// 192^3 single-step fluid solver, fp32 velocity.
// Layout: [c, i, j, k], k fastest.
// R5: (a) advect gathers moved to LDS (stage 3x3 row-neighborhood coalesced,
//         ds_read gather; rare out-of-window lanes fall back to global loads);
//     (b) pressure solve (div, p ping-pong) stored fp16, computed fp32 --
//         halves traffic of the 19 Jacobi sweeps + div/p2/grad.
//     Diffuse unchanged from R4 (float4 + XCD-slab swizzle).

constexpr int   N      = 192;
constexpr int   N2     = N * N;
constexpr int   N3     = N * N * N;
constexpr float GDT    = 9.81f * 0.01f;            // GRAV * DT
constexpr float SCL    = 0.01f / 0.1f;             // DT / H = 0.1
constexpr float ALPHA  = 0.01f * 0.01f / (0.1f * 0.1f);  // VISC*DT/H^2 = 0.01
constexpr float INVDIF = 1.0f / (1.0f + 6.0f * ALPHA);
constexpr float INV2H  = 1.0f / (2.0f * 0.1f);     // 5.0
constexpr float SIXTH  = 1.0f / 6.0f;

constexpr int NT4 = (N3 / 4) / 256;   // 6912 blocks, 4 cells/thread
constexpr int SLAB = NT4 / 8;         // 864 blocks per XCD i-slab

__device__ __forceinline__ int swz(int b) {
    return (b & 7) * SLAB + (b >> 3);
}

__device__ __forceinline__ void decomp(int id, int& i, int& j, int& k0) {
    i = id / N2;
    const int r = id - i * N2;
    j = r / N;
    k0 = r - j * N;
}

// ---- fp16 helpers (storage fp16, math fp32) ----
union H4u { ushort4 u; __half h[4]; };
__device__ __forceinline__ float4 ldh4(const __half* p) {
    H4u t; t.u = *(const ushort4*)p;
    return make_float4(__half2float(t.h[0]), __half2float(t.h[1]),
                       __half2float(t.h[2]), __half2float(t.h[3]));
}
__device__ __forceinline__ void sth4(__half* p, float x, float y, float z, float w) {
    H4u t;
    t.h[0] = __float2half(x); t.h[1] = __float2half(y);
    t.h[2] = __float2half(z); t.h[3] = __float2half(w);
    *(ushort4*)p = t.u;
}
__device__ __forceinline__ float ldh(const __half* p) { return __half2float(*p); }

// ---------------- advect (+gravity), LDS gather ----------------
// Block = 192 threads = one (i,j) k-row. Stage vin[c, i-1..i+1, j-1..j+1, :]
// (27 rows x 192 floats = 20.7 KB). Gather via ds_read; lanes whose backtrace
// leaves the staged window (|disp| >= 1 cell) fall back to global gather.
__global__ __launch_bounds__(192) void k_advect(const float* __restrict__ vin,
                                                float* __restrict__ vout) {
    __shared__ float s[27 * 192];   // [(c*3+di)*3+dj][k]

    const int k   = threadIdx.x;
    const int lin = blockIdx.y * 192 + blockIdx.x;
    const int x   = lin & 7;                         // XCD slab
    const int q   = lin >> 3;
    const int il  = q % 24;
    const int j   = q / 24;
    const int i   = x * 24 + il;
    const int id  = (i * N + j) * N + k;

    // stage 27 rows, float4-coalesced: 48 float4 per row, 4 rows per pass
    {
        const int rsub = threadIdx.x / 48;           // 0..3
        const int col  = (threadIdx.x - rsub * 48) * 4;
#pragma unroll
        for (int p = 0; p < 7; ++p) {
            const int r = p * 4 + rsub;
            if (r < 27) {
                const int c   = r / 9;
                const int rem = r - c * 9;
                const int di  = rem / 3;
                const int dj  = rem - di * 3;
                const int gi  = min(max(i + di - 1, 0), N - 1);
                const int gj  = min(max(j + dj - 1, 0), N - 1);
                *(float4*)&s[r * 192 + col] =
                    *(const float4*)&vin[c * N3 + gi * N2 + gj * N + col];
            }
        }
    }
    __syncthreads();

    const float vx = s[4 * 192 + k];          // row(0,1,1)
    const float vy = s[13 * 192 + k];         // row(1,1,1)
    const float vz = s[22 * 192 + k] - GDT;   // row(2,1,1)

    float px = (float)i - vx * SCL;
    float py = (float)j - vy * SCL;
    float pz = (float)k - vz * SCL;
    const float hi = (float)(N - 2);
    px = fminf(fmaxf(px, 0.0f), hi);
    py = fminf(fmaxf(py, 0.0f), hi);
    pz = fminf(fmaxf(pz, 0.0f), hi);

    const int ix = (int)px;
    const int iy = (int)py;
    const int iz = (int)pz;

    float g[3][8];
    const bool in = (ix >= i - 1) & (ix <= i) & (iy >= j - 1) & (iy <= j);
    if (in) {
        const int li = ix - i + 1;            // 0 or 1
        const int lj = iy - j + 1;            // 0 or 1
#pragma unroll
        for (int c = 0; c < 3; ++c) {
            const int r00 = ((c * 3 + li) * 3 + lj) * 192 + iz;
            const int r01 = r00 + 192;        // dj+1
            const int r10 = r00 + 3 * 192;    // di+1
            const int r11 = r10 + 192;
            g[c][0] = s[r00];     g[c][1] = s[r00 + 1];
            g[c][2] = s[r01];     g[c][3] = s[r01 + 1];
            g[c][4] = s[r10];     g[c][5] = s[r10 + 1];
            g[c][6] = s[r11];     g[c][7] = s[r11 + 1];
        }
    } else {                                  // rare: backtrace left the window
        const int base = (ix * N + iy) * N + iz;
#pragma unroll
        for (int c = 0; c < 3; ++c) {
            const float* f = vin + c * N3 + base;
            g[c][0] = f[0];      g[c][1] = f[1];
            g[c][2] = f[N];      g[c][3] = f[N + 1];
            g[c][4] = f[N2];     g[c][5] = f[N2 + 1];
            g[c][6] = f[N2 + N]; g[c][7] = f[N2 + N + 1];
        }
    }

    const float wx1 = px - (float)ix, wy1 = py - (float)iy, wz1 = pz - (float)iz;
    const float wx0 = 1.0f - wx1,     wy0 = 1.0f - wy1,     wz0 = 1.0f - wz1;
    const float w000 = wx0 * wy0 * wz0;
    const float w001 = wx0 * wy0 * wz1;
    const float w010 = wx0 * wy1 * wz0;
    const float w011 = wx0 * wy1 * wz1;
    const float w100 = wx1 * wy0 * wz0;
    const float w101 = wx1 * wy0 * wz1;
    const float w110 = wx1 * wy1 * wz0;
    const float w111 = wx1 * wy1 * wz1;

#pragma unroll
    for (int c = 0; c < 3; ++c) {
        float r = g[c][0] * w000 + g[c][1] * w001
                + g[c][2] * w010 + g[c][3] * w011
                + g[c][4] * w100 + g[c][5] * w101
                + g[c][6] * w110 + g[c][7] * w111;
        if (c == 2) r -= GDT;
        vout[c * N3 + id] = r;
    }
}

// ---------------- diffuse, float4, component = blockIdx.y (unchanged) --------
__global__ __launch_bounds__(256) void k_diffuse4(const float* __restrict__ vin,
                                                  float* __restrict__ vout) {
    const int gtid = swz(blockIdx.x) * 256 + threadIdx.x;
    const int id   = gtid << 2;
    int i, j, k0; decomp(id, i, j, k0);
    const int b = blockIdx.y * N3 + id;

    const float4 c = *(const float4*)(vin + b);
    float4 out = c;
    if (i != 0 && i != N - 1 && j != 0 && j != N - 1) {
        const float4 ip = *(const float4*)(vin + b + N2);
        const float4 im = *(const float4*)(vin + b - N2);
        const float4 jp = *(const float4*)(vin + b + N);
        const float4 jm = *(const float4*)(vin + b - N);
        const float  km = (k0 > 0)     ? vin[b - 1] : 0.0f;
        const float  kp = (k0 < N - 4) ? vin[b + 4] : 0.0f;
        out.x = (c.x + ALPHA * (im.x + ip.x + jm.x + jp.x + km  + c.y)) * INVDIF;
        out.y = (c.y + ALPHA * (im.y + ip.y + jm.y + jp.y + c.x + c.z)) * INVDIF;
        out.z = (c.z + ALPHA * (im.z + ip.z + jm.z + jp.z + c.y + c.w)) * INVDIF;
        out.w = (c.w + ALPHA * (im.w + ip.w + jm.w + jp.w + c.z + kp )) * INVDIF;
        if (k0 == 0)     out.x = c.x;
        if (k0 == N - 4) out.w = c.w;
    }
    *(float4*)(vout + b) = out;
}

// ---------------- divergence: fp32 vel -> fp16 dv ----------------
__global__ __launch_bounds__(256) void k_div4(const float* __restrict__ v,
                                              __half* __restrict__ dv) {
    const int gtid = swz(blockIdx.x) * 256 + threadIdx.x;
    const int id   = gtid << 2;
    int i, j, k0; decomp(id, i, j, k0);

    float ox = 0.f, oy = 0.f, oz = 0.f, ow = 0.f;
    if (i != 0 && i != N - 1 && j != 0 && j != N - 1) {
        const float4 xp = *(const float4*)(v + id + N2);
        const float4 xm = *(const float4*)(v + id - N2);
        const float4 yp = *(const float4*)(v + N3 + id + N);
        const float4 ym = *(const float4*)(v + N3 + id - N);
        const float4 z  = *(const float4*)(v + 2 * N3 + id);
        const float  zm = (k0 > 0)     ? v[2 * N3 + id - 1] : 0.0f;
        const float  zp = (k0 < N - 4) ? v[2 * N3 + id + 4] : 0.0f;
        ox = ((xp.x - xm.x) + (yp.x - ym.x) + (z.y - zm )) * INV2H;
        oy = ((xp.y - xm.y) + (yp.y - ym.y) + (z.z - z.x)) * INV2H;
        oz = ((xp.z - xm.z) + (yp.z - ym.z) + (z.w - z.y)) * INV2H;
        ow = ((xp.w - xm.w) + (yp.w - ym.w) + (zp  - z.z)) * INV2H;
        if (k0 == 0)     ox = 0.f;
        if (k0 == N - 4) ow = 0.f;
    }
    sth4(dv + id, ox, oy, oz, ow);
}

// ---------------- pressure iterations 1+2 fused, fp16 io ----------------
__global__ __launch_bounds__(256) void k_p2_4(const __half* __restrict__ dv,
                                              __half* __restrict__ p) {
    const int gtid = swz(blockIdx.x) * 256 + threadIdx.x;
    const int id   = gtid << 2;
    int i, j, k0; decomp(id, i, j, k0);

    float ox = 0.f, oy = 0.f, oz = 0.f, ow = 0.f;
    if (i != 0 && i != N - 1 && j != 0 && j != N - 1) {
        const float4 c  = ldh4(dv + id);
        const float4 ip = ldh4(dv + id + N2);
        const float4 im = ldh4(dv + id - N2);
        const float4 jp = ldh4(dv + id + N);
        const float4 jm = ldh4(dv + id - N);
        const float  km = (k0 > 0)     ? ldh(dv + id - 1) : 0.0f;
        const float  kp = (k0 < N - 4) ? ldh(dv + id + 4) : 0.0f;
        ox = (c.x + (im.x + ip.x + jm.x + jp.x + km  + c.y) * SIXTH) * SIXTH;
        oy = (c.y + (im.y + ip.y + jm.y + jp.y + c.x + c.z) * SIXTH) * SIXTH;
        oz = (c.z + (im.z + ip.z + jm.z + jp.z + c.y + c.w) * SIXTH) * SIXTH;
        ow = (c.w + (im.w + ip.w + jm.w + jp.w + c.z + kp ) * SIXTH) * SIXTH;
        if (k0 == 0)     ox = 0.f;
        if (k0 == N - 4) ow = 0.f;
    }
    sth4(p + id, ox, oy, oz, ow);
}

// ---------------- pressure Jacobi sweep, fp16 io ----------------
__global__ __launch_bounds__(256) void k_jacobi4(const __half* __restrict__ pin,
                                                 const __half* __restrict__ dv,
                                                 __half* __restrict__ pout) {
    const int gtid = swz(blockIdx.x) * 256 + threadIdx.x;
    const int id   = gtid << 2;
    int i, j, k0; decomp(id, i, j, k0);

    float ox = 0.f, oy = 0.f, oz = 0.f, ow = 0.f;
    if (i != 0 && i != N - 1 && j != 0 && j != N - 1) {
        const float4 c  = ldh4(pin + id);
        const float4 ip = ldh4(pin + id + N2);
        const float4 im = ldh4(pin + id - N2);
        const float4 jp = ldh4(pin + id + N);
        const float4 jm = ldh4(pin + id - N);
        const float4 d  = ldh4(dv + id);
        const float  km = (k0 > 0)     ? ldh(pin + id - 1) : 0.0f;
        const float  kp = (k0 < N - 4) ? ldh(pin + id + 4) : 0.0f;
        ox = (d.x + im.x + ip.x + jm.x + jp.x + km  + c.y) * SIXTH;
        oy = (d.y + im.y + ip.y + jm.y + jp.y + c.x + c.z) * SIXTH;
        oz = (d.z + im.z + ip.z + jm.z + jp.z + c.y + c.w) * SIXTH;
        ow = (d.w + im.w + ip.w + jm.w + jp.w + c.z + kp ) * SIXTH;
        if (k0 == 0)     ox = 0.f;
        if (k0 == N - 4) ow = 0.f;
    }
    sth4(pout + id, ox, oy, oz, ow);
}

// ---------------- gradient subtract, fp16 p, fp32 vel in-place ---------------
__global__ __launch_bounds__(256) void k_grad4(float* __restrict__ vel,
                                               const __half* __restrict__ p) {
    const int gtid = swz(blockIdx.x) * 256 + threadIdx.x;
    const int id   = gtid << 2;
    int i, j, k0; decomp(id, i, j, k0);
    if (i == 0 || i == N - 1 || j == 0 || j == N - 1) return;

    const float4 xp = ldh4(p + id + N2);
    const float4 xm = ldh4(p + id - N2);
    const float4 yp = ldh4(p + id + N);
    const float4 ym = ldh4(p + id - N);
    const float4 c  = ldh4(p + id);
    const float  pm = (k0 > 0)     ? ldh(p + id - 1) : 0.0f;
    const float  pp = (k0 < N - 4) ? ldh(p + id + 4) : 0.0f;

    const bool bx = (k0 == 0);
    const bool bw = (k0 == N - 4);

    float4 v0 = *(float4*)(vel + id);
    if (!bx) v0.x -= (xp.x - xm.x) * INV2H;
             v0.y -= (xp.y - xm.y) * INV2H;
             v0.z -= (xp.z - xm.z) * INV2H;
    if (!bw) v0.w -= (xp.w - xm.w) * INV2H;
    *(float4*)(vel + id) = v0;

    float4 v1 = *(float4*)(vel + N3 + id);
    if (!bx) v1.x -= (yp.x - ym.x) * INV2H;
             v1.y -= (yp.y - ym.y) * INV2H;
             v1.z -= (yp.z - ym.z) * INV2H;
    if (!bw) v1.w -= (yp.w - ym.w) * INV2H;
    *(float4*)(vel + N3 + id) = v1;

    float4 v2 = *(float4*)(vel + 2 * N3 + id);
    if (!bx) v2.x -= (c.y - pm ) * INV2H;
             v2.y -= (c.z - c.x) * INV2H;
             v2.z -= (c.w - c.y) * INV2H;
    if (!bw) v2.w -= (pp  - c.z) * INV2H;
    *(float4*)(vel + 2 * N3 + id) = v2;
}

extern "C" void kernel_launch(void* const* d_in, const int* in_sizes, int n_in,
                              void* d_out, int out_size, void* d_ws, size_t ws_size,
                              hipStream_t stream) {
    const float* vin  = (const float*)d_in[0];
    float*       vout = (float*)d_out;
    float*       ws   = (float*)d_ws;

    // ws layout: phase 1 velB = fp32 ws[0..3N3);
    // phase 2 (velB dead): fp16 dv = hws[0..N3), pA = hws[N3..2N3), pB = hws[2N3..3N3)
    float*  velB = ws;
    __half* hws  = (__half*)d_ws;
    __half* dv   = hws;
    __half* pA   = hws + N3;
    __half* pB   = hws + 2 * N3;

    const dim3 blk(N, 1, 1);
    const dim3 grid1(N, N, 1);
    const dim3 blk4(256, 1, 1);
    const dim3 grid4_1(NT4, 1, 1);
    const dim3 grid4_3(NT4, 3, 1);

    // gravity + advect: vin -> velB
    k_advect<<<grid1, blk, 0, stream>>>(vin, velB);

    // 5 diffusion sweeps, ping-pong; ends in vout
    k_diffuse4<<<grid4_3, blk4, 0, stream>>>(velB, vout);
    k_diffuse4<<<grid4_3, blk4, 0, stream>>>(vout, velB);
    k_diffuse4<<<grid4_3, blk4, 0, stream>>>(velB, vout);
    k_diffuse4<<<grid4_3, blk4, 0, stream>>>(vout, velB);
    k_diffuse4<<<grid4_3, blk4, 0, stream>>>(velB, vout);

    // projection (fp16 pressure path)
    k_div4<<<grid4_1, blk4, 0, stream>>>(vout, dv);
    k_p2_4<<<grid4_1, blk4, 0, stream>>>(dv, pA);        // iterations 1-2
    __half* pin  = pA;
    __half* pout = pB;
    for (int s = 0; s < 18; ++s) {                       // iterations 3..20
        k_jacobi4<<<grid4_1, blk4, 0, stream>>>(pin, dv, pout);
        __half* t = pin; pin = pout; pout = t;
    }
    k_grad4<<<grid4_1, blk4, 0, stream>>>(vout, pin);    // in-place on d_out
}